// Round 6
// baseline (268.770 us; speedup 1.0000x reference)
//
#include <hip/hip_runtime.h>
#include <hip/hip_bf16.h>
#include <hip/hip_fp16.h>

#define UNITS 512
#define D_DEC 1024
#define D_ENC 1024
#define BATCH 32
#define S_LEN 2048

typedef _Float16 f16x8 __attribute__((ext_vector_type(8)));
typedef float f32x4 __attribute__((ext_vector_type(4)));

__device__ inline float tanh_fast(float x) {
    float e = __expf(2.f * x);
    return 1.f - 2.f * __builtin_amdgcn_rcpf(e + 1.f);
}

// ---------------- prep: transpose + convert W2 [1024][512] f32 -> W2h [512][1024] f16
__global__ __launch_bounds__(256) void k_prep_w2(const float* __restrict__ W2,
                                                 _Float16* __restrict__ W2h) {
    __shared__ float tile[32][33];
    const int kb = blockIdx.x * 32;
    const int nb = blockIdx.y * 32;
    const int tx = threadIdx.x;
    const int ty = threadIdx.y;
    for (int i = 0; i < 32; i += 8)
        tile[ty + i][tx] = W2[(size_t)(kb + ty + i) * UNITS + nb + tx];
    __syncthreads();
    for (int i = 0; i < 32; i += 8)
        W2h[(size_t)(nb + ty + i) * D_DEC + kb + tx] = (_Float16)tile[tx][ty + i];
}

// ---------------- query
__global__ __launch_bounds__(1024) void k_query(const float* __restrict__ dec,
                                                const float* __restrict__ W1,
                                                const float* __restrict__ b1,
                                                float* __restrict__ query) {
    const int u = blockIdx.x * 32 + (threadIdx.x & 31);
    const int b = threadIdx.x >> 5;
    float acc = b1[u];
    const float* dp = dec + (size_t)b * D_DEC;
    for (int d = 0; d < D_DEC; ++d) acc += dp[d] * W1[(size_t)d * UNITS + u];
    query[(size_t)b * UNITS + u] = acc;
}

// ---------------- scores: 8-phase template port. M=65536 K=1024 N=512.
// Block: 256 rows x 256 cols (2-way n-split), 8 waves 2Mx4N (wave tile 128x64),
// BK=64 -> 16 K-tiles, 4 phases/K-tile, 16 MFMA/phase/wave.
#define BM2 256
#define BK2 64
#define NT (D_DEC / BK2)   // 16

// swizzled LDS byte offset for a 128B-row tile: row*128 + (kbyte ^ ((row&7)<<4))
__device__ __forceinline__ const f16x8* lds_frag(const _Float16* base, int row, int kbyte) {
    return reinterpret_cast<const f16x8*>(
        (const char*)base + row * 128 + (kbyte ^ ((row & 7) << 4)));
}

#define PHASE(ACP, BCP, MH, NH, STAGE) do {                                          \
    f16x8 af[4][2], bf[2][2];                                                        \
    _Pragma("unroll") for (int q = 0; q < 4; ++q) {                                  \
        const int rowa = wr * 128 + ((MH) * 4 + q) * 16 + r;                         \
        af[q][0] = *lds_frag(ACP, rowa, g * 16);                                     \
        af[q][1] = *lds_frag(ACP, rowa, 64 + g * 16);                                \
    }                                                                                \
    _Pragma("unroll") for (int j = 0; j < 2; ++j) {                                  \
        const int rowb = wc * 64 + ((NH) * 2 + j) * 16 + r;                          \
        bf[j][0] = *lds_frag(BCP, rowb, g * 16);                                     \
        bf[j][1] = *lds_frag(BCP, rowb, 64 + g * 16);                                \
    }                                                                                \
    STAGE;                                                                           \
    __builtin_amdgcn_s_barrier();                                                    \
    asm volatile("s_waitcnt lgkmcnt(0)" ::: "memory");                               \
    __builtin_amdgcn_sched_barrier(0);                                               \
    __builtin_amdgcn_s_setprio(1);                                                   \
    _Pragma("unroll") for (int kf = 0; kf < 2; ++kf)                                 \
        _Pragma("unroll") for (int q = 0; q < 4; ++q)                                \
            _Pragma("unroll") for (int j = 0; j < 2; ++j)                            \
                acc[(MH) * 4 + q][(NH) * 2 + j] =                                    \
                    __builtin_amdgcn_mfma_f32_16x16x32_f16(                          \
                        af[q][kf], bf[j][kf], acc[(MH) * 4 + q][(NH) * 2 + j], 0, 0, 0); \
    __builtin_amdgcn_s_setprio(0);                                                   \
    __builtin_amdgcn_s_barrier();                                                    \
} while (0)

__global__ __launch_bounds__(512, 2) void k_scores(const float* __restrict__ enc,
                                                   const _Float16* __restrict__ W2h,
                                                   const float* __restrict__ query,
                                                   const float* __restrict__ b2,
                                                   const float* __restrict__ V,
                                                   float* __restrict__ psc) {
    __shared__ __align__(16) _Float16 Ab[2][BM2 * BK2];   // 2 x 32 KB
    __shared__ __align__(16) _Float16 Bb[2][BM2 * BK2];   // 2 x 32 KB
    __shared__ float sc_part[4][BM2];                     // 4 KB

    const int tid  = threadIdx.x;
    const int lane = tid & 63;
    const int w    = tid >> 6;     // 0..7
    const int wr   = w >> 2;       // 0..1: rows [wr*128, +128)
    const int wc   = w & 3;        // 0..3: cols [wc*64, +64)
    const int g    = lane >> 4;    // 0..3
    const int r    = lane & 15;    // 0..15

    // XCD pairing: wg and wg+8 share %8 residue; map to (n=0,n=1) of one m-tile.
    const unsigned wg = blockIdx.x;              // 0..511
    const int mapped = (int)((wg & 7) * 64 + (wg >> 3));
    const int m_blk  = mapped >> 1;              // 0..255
    const int n_blk  = mapped & 1;
    const int row0   = m_blk * BM2;
    const int n0     = n_blk * 256;
    const int bat    = row0 >> 11;

    // A staging: thread -> row ar = tid>>1, 32 f32 at (tid&1)*32
    const int ar = tid >> 1;
    const float* aptr = enc + (size_t)(row0 + ar) * D_ENC + (tid & 1) * 32;

    f32x4 acc[8][4];
#pragma unroll
    for (int i = 0; i < 8; ++i)
#pragma unroll
        for (int j = 0; j < 4; ++j) acc[i][j] = (f32x4){0.f, 0.f, 0.f, 0.f};

    // B gload: granule = i*512+tid; n = granule>>3 (row), kb = (granule&7)*16 bytes.
    // Pre-swizzled source so linear LDS holds row n with kbyte ^ ((n&7)<<4).
    auto gldB = [&](int kt, int i, _Float16* Bn) {
        const int gr = i * 512 + tid;
        const int n  = gr >> 3;
        const int kb = (gr & 7) * 16;
        const int ks = (kb ^ ((n & 7) << 4)) >> 1;   // f16 elems
        const _Float16* src = W2h + (size_t)(n0 + n) * D_DEC + kt + ks;
        __builtin_amdgcn_global_load_lds(
            (const __attribute__((address_space(1))) void*)src,
            (__attribute__((address_space(3))) void*)(Bn + gr * 8), 16, 0, 0);
    };
    auto pack = [](const float4& x, const float4& y) -> f16x8 {
        return (f16x8){(_Float16)x.x, (_Float16)x.y, (_Float16)x.z, (_Float16)x.w,
                       (_Float16)y.x, (_Float16)y.y, (_Float16)y.z, (_Float16)y.w};
    };
    auto wrA = [&](_Float16* An, int j, const float4& x, const float4& y) {
        const int off = ar * 128 + ((((tid & 1) * 64) + j * 16) ^ ((ar & 7) << 4));
        *reinterpret_cast<f16x8*>((char*)An + off) = pack(x, y);
    };

    // ---- prologue: stage tile 0 into buf 0 (fully exposed, once)
    {
        gldB(0, 0, &Bb[0][0]); gldB(0, 1, &Bb[0][0]);
        gldB(0, 2, &Bb[0][0]); gldB(0, 3, &Bb[0][0]);
        float4 a0 = *reinterpret_cast<const float4*>(aptr);
        float4 a1 = *reinterpret_cast<const float4*>(aptr + 4);
        float4 a2 = *reinterpret_cast<const float4*>(aptr + 8);
        float4 a3 = *reinterpret_cast<const float4*>(aptr + 12);
        float4 a4 = *reinterpret_cast<const float4*>(aptr + 16);
        float4 a5 = *reinterpret_cast<const float4*>(aptr + 20);
        float4 a6 = *reinterpret_cast<const float4*>(aptr + 24);
        float4 a7 = *reinterpret_cast<const float4*>(aptr + 28);
        wrA(&Ab[0][0], 0, a0, a1); wrA(&Ab[0][0], 1, a2, a3);
        wrA(&Ab[0][0], 2, a4, a5); wrA(&Ab[0][0], 3, a6, a7);
        asm volatile("s_waitcnt vmcnt(0) lgkmcnt(0)" ::: "memory");
        __builtin_amdgcn_s_barrier();
    }

    // ---- main loop: 16 K-tiles x 4 phases
    for (int t = 0; t < NT; ++t) {
        const int c = t & 1;
        _Float16* Ac = &Ab[c][0];
        _Float16* Bc = &Bb[c][0];
        _Float16* An = &Ab[c ^ 1][0];
        _Float16* Bn = &Bb[c ^ 1][0];
        const bool more = (t + 1 < NT);
        const int kg = (t + 1) * BK2;
        float4 a0, a1, a2, a3, a4, a5, a6, a7;

        PHASE(Ac, Bc, 0, 0, {
            if (more) {
                a0 = *reinterpret_cast<const float4*>(aptr + kg);
                a1 = *reinterpret_cast<const float4*>(aptr + kg + 4);
                a2 = *reinterpret_cast<const float4*>(aptr + kg + 8);
                a3 = *reinterpret_cast<const float4*>(aptr + kg + 12);
                gldB(kg, 0, Bn); gldB(kg, 1, Bn);
            }
        });
        PHASE(Ac, Bc, 0, 1, {
            if (more) {
                a4 = *reinterpret_cast<const float4*>(aptr + kg + 16);
                a5 = *reinterpret_cast<const float4*>(aptr + kg + 20);
                a6 = *reinterpret_cast<const float4*>(aptr + kg + 24);
                a7 = *reinterpret_cast<const float4*>(aptr + kg + 28);
                gldB(kg, 2, Bn); gldB(kg, 3, Bn);
            }
        });
        PHASE(Ac, Bc, 1, 0, {});
        PHASE(Ac, Bc, 1, 1, {
            if (more) {
                wrA(An, 0, a0, a1); wrA(An, 1, a2, a3);
                wrA(An, 2, a4, a5); wrA(An, 3, a6, a7);
                asm volatile("s_waitcnt vmcnt(0)" ::: "memory");
            }
        });
    }

    // ---- epilogue: partial scores over this block's 256 cols
    float qv[4], vv[4];
#pragma unroll
    for (int fn = 0; fn < 4; ++fn) {
        const int col = n0 + wc * 64 + fn * 16 + r;
        qv[fn] = query[(size_t)bat * UNITS + col] + b2[col];
        vv[fn] = V[col];
    }
    float ps[8][4];
#pragma unroll
    for (int fm = 0; fm < 8; ++fm)
#pragma unroll
        for (int i = 0; i < 4; ++i) ps[fm][i] = 0.f;
#pragma unroll
    for (int fn = 0; fn < 4; ++fn)
#pragma unroll
        for (int fm = 0; fm < 8; ++fm)
#pragma unroll
            for (int i = 0; i < 4; ++i)
                ps[fm][i] += tanh_fast(acc[fm][fn][i] + qv[fn]) * vv[fn];
#pragma unroll
    for (int off = 1; off < 16; off <<= 1)
#pragma unroll
        for (int fm = 0; fm < 8; ++fm)
#pragma unroll
            for (int i = 0; i < 4; ++i)
                ps[fm][i] += __shfl_xor(ps[fm][i], off, 64);
    if (r == 0)
#pragma unroll
        for (int fm = 0; fm < 8; ++fm)
#pragma unroll
            for (int i = 0; i < 4; ++i)
                sc_part[wc][wr * 128 + fm * 16 + g * 4 + i] = ps[fm][i];
    __syncthreads();
    if (tid < BM2)
        psc[(size_t)n_blk * 65536 + row0 + tid] =
            sc_part[0][tid] + sc_part[1][tid] + sc_part[2][tid] + sc_part[3][tid];
}

// ---------------- softmax (merges 2 n-planes; bv dropped: shift-invariant)
__global__ __launch_bounds__(256) void k_softmax(const float* __restrict__ psc,
                                                 float* __restrict__ weights) {
    const int b = blockIdx.x;
    const int tid = threadIdx.x;
    __shared__ float wmax[4], wsum[4];
    float v[8];
    float lm = -1e30f;
#pragma unroll
    for (int i = 0; i < 8; ++i) {
        const size_t idx = (size_t)b * S_LEN + tid + i * 256;
        v[i] = psc[idx] + psc[65536 + idx];
        lm = fmaxf(lm, v[i]);
    }
    for (int off = 32; off; off >>= 1) lm = fmaxf(lm, __shfl_xor(lm, off, 64));
    if ((tid & 63) == 0) wmax[tid >> 6] = lm;
    __syncthreads();
    const float m = fmaxf(fmaxf(wmax[0], wmax[1]), fmaxf(wmax[2], wmax[3]));
    float ls = 0.f;
#pragma unroll
    for (int i = 0; i < 8; ++i) { v[i] = __expf(v[i] - m); ls += v[i]; }
    for (int off = 32; off; off >>= 1) ls += __shfl_xor(ls, off, 64);
    if ((tid & 63) == 0) wsum[tid >> 6] = ls;
    __syncthreads();
    const float inv = 1.f / (wsum[0] + wsum[1] + wsum[2] + wsum[3]);
#pragma unroll
    for (int i = 0; i < 8; ++i)
        weights[(size_t)b * S_LEN + tid + i * 256] = v[i] * inv;
}

// ---------------- context partials
#define SCH 128
#define NCH (S_LEN / SCH)
__global__ __launch_bounds__(256) void k_ctx_part(const float* __restrict__ enc,
                                                  const float* __restrict__ weights,
                                                  float* __restrict__ part) {
    const int b  = blockIdx.x >> 4;
    const int ch = blockIdx.x & 15;
    const int s0 = ch * SCH;
    const int d4 = threadIdx.x * 4;
    __shared__ float wl[SCH];
    if (threadIdx.x < SCH) wl[threadIdx.x] = weights[(size_t)b * S_LEN + s0 + threadIdx.x];
    __syncthreads();
    float4 a = {0.f, 0.f, 0.f, 0.f};
    const float* base = enc + (size_t)b * S_LEN * D_ENC + (size_t)s0 * D_ENC + d4;
#pragma unroll 4
    for (int s = 0; s < SCH; ++s) {
        const float4 e = *reinterpret_cast<const float4*>(base + (size_t)s * D_ENC);
        const float w = wl[s];
        a.x += w * e.x; a.y += w * e.y; a.z += w * e.z; a.w += w * e.w;
    }
    *reinterpret_cast<float4*>(&part[(size_t)blockIdx.x * D_ENC + d4]) = a;
}

__global__ __launch_bounds__(256) void k_ctx_combine(const float* __restrict__ part,
                                                     float* __restrict__ ctx) {
    const int idx = blockIdx.x * 256 + threadIdx.x;
    const int b = idx >> 10;
    const int d = idx & 1023;
    float s = 0.f;
#pragma unroll
    for (int c = 0; c < NCH; ++c) s += part[(size_t)(b * NCH + c) * D_ENC + d];
    ctx[idx] = s;
}

extern "C" void kernel_launch(void* const* d_in, const int* in_sizes, int n_in,
                              void* d_out, int out_size, void* d_ws, size_t ws_size,
                              hipStream_t stream) {
    const float* dec = (const float*)d_in[0];
    const float* enc = (const float*)d_in[1];
    const float* W1  = (const float*)d_in[2];
    const float* b1  = (const float*)d_in[3];
    const float* W2  = (const float*)d_in[4];
    const float* b2  = (const float*)d_in[5];
    const float* V   = (const float*)d_in[6];
    // bv unused: softmax shift-invariant

    float* out = (float*)d_out;
    float* out_ctx = out;
    float* out_w   = out + BATCH * D_ENC;

    char* ws = (char*)d_ws;
    _Float16* W2h = (_Float16*)(ws);                        // 1 MB
    float* query  = (float*)(ws + (1 << 20));               // 64 KB
    float* psc    = (float*)(ws + (1 << 20) + (1 << 16));   // 512 KB (2 planes)
    float* part   = (float*)(ws + (1 << 20) + (1 << 16) + (1 << 19)); // 2 MB

    k_prep_w2<<<dim3(D_DEC / 32, UNITS / 32), dim3(32, 8), 0, stream>>>(W2, W2h);
    k_query<<<UNITS / 32, 1024, 0, stream>>>(dec, W1, b1, query);
    k_scores<<<512, 512, 0, stream>>>(enc, W2h, query, b2, V, psc);
    k_softmax<<<BATCH, 256, 0, stream>>>(psc, out_w);
    k_ctx_part<<<BATCH * NCH, 256, 0, stream>>>(enc, out_w, part);
    k_ctx_combine<<<(BATCH * D_ENC) / 256, 256, 0, stream>>>(part, out_ctx);
}